// Round 2
// baseline (3566.241 us; speedup 1.0000x reference)
//
#include <hip/hip_runtime.h>
#include <math.h>

// Problem constants
#define NB   128   // batch
#define NC   512   // channels
#define NT   256   // T = H*W
#define NL   512   // S + T
#define NG   32    // groups
#define SCALE2 0.04419417382415922f  // 1/sqrt(512)

// GEMM tile config
#define BM 64
#define BN 64
#define BK 32
#define PAD 4

struct Params {
  const float *x, *morph, *gw, *gb, *qkvw, *qkvb, *ekvw, *ekvb, *projw, *projb;
  float *stats, *q, *kf, *vf, *pr, *abuf, *out;
  int b0;  // global batch offset of this chunk
};

enum { M_QKV = 0, M_EKV = 1, M_LOGITS = 2, M_PV = 3, M_PROJ = 4 };

// ---------------- GroupNorm statistics: one block per (local b, g) ----------
// Each group is 16 channels x 256 t = 4096 CONTIGUOUS floats in x [B,C,T].
__global__ __launch_bounds__(256) void gn_stats_k(const float* __restrict__ x,
                                                  float* __restrict__ stats,
                                                  int b0) {
  const int bg = blockIdx.x;                              // local: lb*32 + g
  const float* p = x + ((size_t)b0 * NG + bg) * 4096;     // global offset
  float s = 0.f, s2 = 0.f;
  for (int i = threadIdx.x; i < 4096; i += 256) {
    float v = p[i];
    s += v; s2 += v * v;
  }
  for (int off = 32; off; off >>= 1) {
    s  += __shfl_down(s, off);
    s2 += __shfl_down(s2, off);
  }
  __shared__ float red[8];
  const int wave = threadIdx.x >> 6, lane = threadIdx.x & 63;
  if (lane == 0) { red[wave * 2] = s; red[wave * 2 + 1] = s2; }
  __syncthreads();
  if (threadIdx.x == 0) {
    float S = 0.f, S2 = 0.f;
    for (int w = 0; w < 4; ++w) { S += red[w * 2]; S2 += red[w * 2 + 1]; }
    float mu = S * (1.0f / 4096.0f);
    float var = S2 * (1.0f / 4096.0f) - mu * mu;
    stats[bg * 2]     = mu;
    stats[bg * 2 + 1] = rsqrtf(var + 1e-5f);
  }
}

// ---------------- Templated 64x64x32 fp32 tiled GEMM ----------------
// out[m,n] = sum_k A[m,k] * B[k,n], per-batch, K = 512 for every mode.
// blockIdx.z = LOCAL batch (workspace index); global batch = b0 + z.
template <int MODE>
__global__ __launch_bounds__(256) void gemm_k(Params P) {
  __shared__ __align__(16) float As[BK][BM + PAD];
  __shared__ __align__(16) float Bs[BK][BN + PAD];
  const int lb = blockIdx.z;          // local batch -> workspace
  const int gb = P.b0 + lb;           // global batch -> x/morph/out
  const int m0 = blockIdx.y * BM;
  const int n0 = blockIdx.x * BN;
  const int tid = threadIdx.x;
  const int tx = tid & 15, ty = tid >> 4;

  float acc[4][4] = {};

  for (int k0 = 0; k0 < 512; k0 += BK) {
    // ---- stage A tile into As[k][m] ----
    if (MODE == M_LOGITS) {
      // A = q^T : q stored [C, T] (K-major, m contiguous)
      #pragma unroll
      for (int p = tid; p < BK * BM; p += 256) {
        int r = p >> 6, c = p & 63; // r = k, c = m
        As[r][c] = P.q[((size_t)lb * NC + k0 + r) * NT + m0 + c];
      }
    } else {
      // A row-major [M, K] (k contiguous): weights, or v_full for PV
      const float* A;
      if (MODE == M_QKV)       A = P.qkvw;
      else if (MODE == M_EKV)  A = P.ekvw;
      else if (MODE == M_PROJ) A = P.projw;
      else                     A = P.vf + (size_t)lb * NC * NL; // [C, L]
      #pragma unroll
      for (int p = tid; p < BM * BK; p += 256) {
        int r = p >> 5, c = p & 31; // r = m, c = k
        As[c][r] = A[(m0 + r) * 512 + k0 + c];
      }
    }
    // ---- stage B tile into Bs[k][n] ----
    if (MODE == M_PV) {
      // B = probs^T : probs stored [T, L] (N-major, k contiguous)
      #pragma unroll
      for (int p = tid; p < BN * BK; p += 256) {
        int r = p >> 5, c = p & 31; // r = n, c = k
        Bs[c][r] = P.pr[((size_t)lb * NT + n0 + r) * NL + k0 + c];
      }
    } else {
      #pragma unroll
      for (int p = tid; p < BK * BN; p += 256) {
        int r = p >> 6, c = p & 63; // r = k, c = n
        if (MODE == M_QKV) {
          int ch = k0 + r;
          float xv = P.x[((size_t)gb * NC + ch) * NT + n0 + c];
          float mu = P.stats[((size_t)lb * NG + (ch >> 4)) * 2];
          float rs = P.stats[((size_t)lb * NG + (ch >> 4)) * 2 + 1];
          Bs[r][c] = (xv - mu) * rs * P.gw[ch] + P.gb[ch];
        } else if (MODE == M_EKV) {
          Bs[r][c] = P.morph[((size_t)gb * NC + k0 + r) * NT + n0 + c];
        } else if (MODE == M_LOGITS) {
          Bs[r][c] = P.kf[((size_t)lb * NC + k0 + r) * NL + n0 + c];
        } else { // M_PROJ
          Bs[r][c] = P.abuf[((size_t)lb * NC + k0 + r) * NT + n0 + c];
        }
      }
    }
    __syncthreads();

    #pragma unroll
    for (int kk = 0; kk < BK; ++kk) {
      float4 av = *(const float4*)&As[kk][ty * 4];
      float4 bv = *(const float4*)&Bs[kk][tx * 4];
      float a_[4] = {av.x, av.y, av.z, av.w};
      float b_[4] = {bv.x, bv.y, bv.z, bv.w};
      #pragma unroll
      for (int i = 0; i < 4; ++i)
        #pragma unroll
        for (int j = 0; j < 4; ++j)
          acc[i][j] = fmaf(a_[i], b_[j], acc[i][j]);
    }
    __syncthreads();
  }

  // ---- epilogue ----
  const int mbase = m0 + ty * 4;
  const int nbase = n0 + tx * 4;
  #pragma unroll
  for (int i = 0; i < 4; ++i) {
    const int m = mbase + i;
    if (MODE == M_QKV) {
      float bias = P.qkvb[m];
      float* dst;
      if (m < 512)       dst = P.q  + ((size_t)lb * NC + m) * NT + nbase;
      else if (m < 1024) dst = P.kf + ((size_t)lb * NC + m - 512) * NL + 256 + nbase;
      else               dst = P.vf + ((size_t)lb * NC + m - 1024) * NL + 256 + nbase;
      #pragma unroll
      for (int j = 0; j < 4; ++j) dst[j] = acc[i][j] + bias;
    } else if (MODE == M_EKV) {
      float bias = P.ekvb[m];
      float* dst;
      if (m < 512) dst = P.kf + ((size_t)lb * NC + m) * NL + nbase;
      else         dst = P.vf + ((size_t)lb * NC + m - 512) * NL + nbase;
      #pragma unroll
      for (int j = 0; j < 4; ++j) dst[j] = acc[i][j] + bias;
    } else if (MODE == M_LOGITS) {
      float* dst = P.pr + ((size_t)lb * NT + m) * NL + nbase;
      #pragma unroll
      for (int j = 0; j < 4; ++j) dst[j] = acc[i][j] * SCALE2;
    } else if (MODE == M_PV) {
      float* dst = P.abuf + ((size_t)lb * NC + m) * NT + nbase;
      #pragma unroll
      for (int j = 0; j < 4; ++j) dst[j] = acc[i][j];
    } else { // M_PROJ
      float bias = P.projb[m];
      const size_t idx = ((size_t)gb * NC + m) * NT + nbase;
      #pragma unroll
      for (int j = 0; j < 4; ++j)
        P.out[idx + j] = 2.0f * P.morph[idx + j] - P.x[idx + j] - (acc[i][j] + bias);
    }
  }
}

// ---------------- Row softmax over L=512, one wave per row ----------------
__global__ __launch_bounds__(256) void softmax_k(float* __restrict__ pr) {
  const int row  = blockIdx.x * 4 + (threadIdx.x >> 6);
  const int lane = threadIdx.x & 63;
  float* p = pr + (size_t)row * NL;
  float v[8];
  float m = -1e30f;
  #pragma unroll
  for (int i = 0; i < 8; ++i) {
    v[i] = p[lane + 64 * i];
    m = fmaxf(m, v[i]);
  }
  #pragma unroll
  for (int off = 32; off; off >>= 1) m = fmaxf(m, __shfl_xor(m, off));
  float s = 0.f;
  #pragma unroll
  for (int i = 0; i < 8; ++i) { v[i] = __expf(v[i] - m); s += v[i]; }
  #pragma unroll
  for (int off = 32; off; off >>= 1) s += __shfl_xor(s, off);
  const float inv = 1.0f / s;
  #pragma unroll
  for (int i = 0; i < 8; ++i) p[lane + 64 * i] = v[i] * inv;
}

extern "C" void kernel_launch(void* const* d_in, const int* in_sizes, int n_in,
                              void* d_out, int out_size, void* d_ws, size_t ws_size,
                              hipStream_t stream) {
  Params P;
  P.x     = (const float*)d_in[0];
  P.morph = (const float*)d_in[1];
  P.gw    = (const float*)d_in[2];
  P.gb    = (const float*)d_in[3];
  P.qkvw  = (const float*)d_in[4];
  P.qkvb  = (const float*)d_in[5];
  P.ekvw  = (const float*)d_in[6];
  P.ekvb  = (const float*)d_in[7];
  P.projw = (const float*)d_in[8];
  P.projb = (const float*)d_in[9];
  P.out   = (float*)d_out;

  // Per-batch workspace (floats): stats 64, q 131072, kf 262144, vf 262144,
  // pr 131072, abuf 131072  -> 917,568 floats = 3,670,272 bytes.
  const size_t per_batch_f = (size_t)2 * NG + (size_t)NC * NT * 3 + (size_t)NC * NL * 2
                           + (size_t)NT * NL;
  // Largest power-of-two batch chunk that fits in ws_size (deterministic).
  int nbc = NB;
  while (nbc > 1 && (size_t)nbc * per_batch_f * sizeof(float) > ws_size) nbc >>= 1;

  float* ws = (float*)d_ws;
  P.stats = ws;  ws += (size_t)nbc * 2 * NG;
  P.q     = ws;  ws += (size_t)nbc * NC * NT;
  P.kf    = ws;  ws += (size_t)nbc * NC * NL;
  P.vf    = ws;  ws += (size_t)nbc * NC * NL;
  P.pr    = ws;  ws += (size_t)nbc * NT * NL;
  P.abuf  = ws;

  for (int b0 = 0; b0 < NB; b0 += nbc) {
    P.b0 = b0;
    gn_stats_k<<<dim3(nbc * NG), dim3(256), 0, stream>>>(P.x, P.stats, b0);
    gemm_k<M_QKV>   <<<dim3(NT / BN, 1536 / BM, nbc), dim3(256), 0, stream>>>(P);
    gemm_k<M_EKV>   <<<dim3(NT / BN, 1024 / BM, nbc), dim3(256), 0, stream>>>(P);
    gemm_k<M_LOGITS><<<dim3(NL / BN, NT / BM,  nbc), dim3(256), 0, stream>>>(P);
    softmax_k       <<<dim3(nbc * NT / 4), dim3(256), 0, stream>>>(P.pr);
    gemm_k<M_PV>    <<<dim3(NT / BN, NC / BM,  nbc), dim3(256), 0, stream>>>(P);
    gemm_k<M_PROJ>  <<<dim3(NT / BN, NC / BM,  nbc), dim3(256), 0, stream>>>(P);
  }
}

// Round 3
// 603.582 us; speedup vs baseline: 5.9085x; 5.9085x over previous
//
#include <hip/hip_runtime.h>
#include <hip/hip_bf16.h>
#include <math.h>

#define NB 128
#define NC 512
#define NT 256
#define NL 512
#define NG 32
#define SCALE2 0.04419417382415922f  // 1/sqrt(512)

typedef __attribute__((ext_vector_type(8))) short bf16x8;   // 8 bf16 = 4 VGPRs
typedef __attribute__((ext_vector_type(4))) float f32x4;
typedef __attribute__((ext_vector_type(4))) unsigned short u16x4;
typedef __hip_bfloat16 bf16;

struct Params {
  const float *x, *morph, *qkvb, *ekvb, *projb;
  const bf16 *wq, *we, *wp;
  bf16 *hT, *mT, *qT, *kfT, *vf, *pr, *aT;
  float *out;
  int b0;
};

enum { M_QKV = 0, M_EKV = 1, M_LOG = 2, M_PV = 3, M_PROJ = 4 };

__device__ inline unsigned short f2bf_bits(float f) {
  bf16 h = __float2bfloat16(f);
  return *reinterpret_cast<unsigned short*>(&h);
}

// ---------------- GroupNorm statistics over all 128 batches ----------------
__global__ __launch_bounds__(256) void gn_stats_k(const float* __restrict__ x,
                                                  float* __restrict__ stats) {
  const int bg = blockIdx.x;               // b*32 + g ; group = 4096 contiguous
  const float* p = x + (size_t)bg * 4096;
  float s = 0.f, s2 = 0.f;
  for (int i = threadIdx.x; i < 4096; i += 256) {
    float v = p[i];
    s += v; s2 += v * v;
  }
  for (int off = 32; off; off >>= 1) {
    s  += __shfl_down(s, off);
    s2 += __shfl_down(s2, off);
  }
  __shared__ float red[8];
  const int wave = threadIdx.x >> 6, lane = threadIdx.x & 63;
  if (lane == 0) { red[wave * 2] = s; red[wave * 2 + 1] = s2; }
  __syncthreads();
  if (threadIdx.x == 0) {
    float S = 0.f, S2 = 0.f;
    for (int w = 0; w < 4; ++w) { S += red[w * 2]; S2 += red[w * 2 + 1]; }
    float mu = S * (1.0f / 4096.0f);
    float var = S2 * (1.0f / 4096.0f) - mu * mu;
    stats[bg * 2]     = mu;
    stats[bg * 2 + 1] = rsqrtf(var + 1e-5f);
  }
}

// ---------------- fp32 -> bf16 weight conversion ----------------
__global__ __launch_bounds__(256) void cvt_k(const float* __restrict__ s,
                                             bf16* __restrict__ d, int n) {
  int i = blockIdx.x * 256 + threadIdx.x;
  if (i < n) d[i] = __float2bfloat16(s[i]);
}

// ---------------- [C][T] fp32 -> [T][C] bf16 transpose (opt. groupnorm) ----
template <int NORM>
__global__ __launch_bounds__(256) void transpose_k(const float* __restrict__ src,
                                                   bf16* __restrict__ dst,
                                                   const float* __restrict__ stats,
                                                   const float* __restrict__ gnw,
                                                   const float* __restrict__ gnb,
                                                   int b0) {
  __shared__ float sm[32][33];
  const int lb = blockIdx.z, gb = b0 + lb;
  const int c0 = blockIdx.y * 32, t0 = blockIdx.x * 32;
  const int tx = threadIdx.x & 31, ty = threadIdx.x >> 5;  // ty in [0,8)
  const float* s = src + ((size_t)gb * NC + c0) * NT + t0;
  #pragma unroll
  for (int j = 0; j < 4; ++j) {
    int c = ty + j * 8;
    float v = s[c * NT + tx];
    if (NORM) {
      int cg = c0 + c;
      float mu = stats[(gb * NG + (cg >> 4)) * 2];
      float rs = stats[(gb * NG + (cg >> 4)) * 2 + 1];
      v = (v - mu) * rs * gnw[cg] + gnb[cg];
    }
    sm[c][tx] = v;
  }
  __syncthreads();
  bf16* d = dst + ((size_t)lb * NT + t0) * NC + c0;
  #pragma unroll
  for (int j = 0; j < 4; ++j)
    d[(size_t)(ty + j * 8) * NC + tx] = __float2bfloat16(sm[tx][ty + j * 8]);
}

// ---------------- Uniform MFMA GEMM: C[i][j] = sum_k A[i][k] * B[j][k] ------
// A: [256][512] bf16 row-major, B: [N][512] bf16 row-major, K = 512 always.
// Block: 256 thr (4 waves), tile 128x128, BK=32, each wave 4x4 MFMA 16x16x32.
template <int MODE>
__global__ __launch_bounds__(256) void gemm_k(Params P) {
  __shared__ unsigned short As[128][40];  // +8 bf16 pad: worst 2-way conflict
  __shared__ unsigned short Bs[128][40];
  const int lb = blockIdx.z, gb = P.b0 + lb;
  const int m0 = blockIdx.y * 128;
  const int n0 = blockIdx.x * 128;
  const int tid = threadIdx.x;
  const int lane = tid & 63, w = tid >> 6;
  const int wr = w >> 1, wc = w & 1;
  const int ln = lane & 15, kq = lane >> 4;

  const bf16 *Ab, *Bb;
  if (MODE == M_QKV)      { Ab = P.hT + (size_t)lb * NT * NC; Bb = P.wq; }
  else if (MODE == M_EKV) { Ab = P.mT + (size_t)lb * NT * NC; Bb = P.we; }
  else if (MODE == M_LOG) { Ab = P.qT + (size_t)lb * NT * NC; Bb = P.kfT + (size_t)lb * NL * NC; }
  else if (MODE == M_PV)  { Ab = P.pr + (size_t)lb * NT * NL; Bb = P.vf + (size_t)lb * NC * NL; }
  else                    { Ab = P.aT + (size_t)lb * NT * NC; Bb = P.wp; }

  const uint4* Ag = (const uint4*)(Ab + (size_t)m0 * 512);  // row stride 64 uint4
  const uint4* Bg = (const uint4*)(Bb + (size_t)n0 * 512);

  f32x4 acc[4][4] = {};

  for (int k0 = 0; k0 < 512; k0 += 32) {
    const int kb = k0 >> 3;
    #pragma unroll
    for (int h = 0; h < 2; ++h) {
      int ch = tid + h * 256;         // 512 16B-chunks per tile
      int row = ch >> 2, cid = ch & 3;
      *(uint4*)&As[row][cid * 8] = Ag[row * 64 + kb + cid];
      *(uint4*)&Bs[row][cid * 8] = Bg[row * 64 + kb + cid];
    }
    __syncthreads();
    bf16x8 af[4], bfr[4];
    #pragma unroll
    for (int i = 0; i < 4; ++i)
      af[i] = *(const bf16x8*)&As[wr * 64 + i * 16 + ln][kq * 8];
    #pragma unroll
    for (int j = 0; j < 4; ++j)
      bfr[j] = *(const bf16x8*)&Bs[wc * 64 + j * 16 + ln][kq * 8];
    #pragma unroll
    for (int i = 0; i < 4; ++i)
      #pragma unroll
      for (int j = 0; j < 4; ++j)
        acc[i][j] = __builtin_amdgcn_mfma_f32_16x16x32_bf16(af[i], bfr[j], acc[i][j], 0, 0, 0);
    __syncthreads();
  }

  // Epilogue. D layout: col = lane&15 (j), row = (lane>>4)*4 + reg (i).
  #pragma unroll
  for (int i = 0; i < 4; ++i) {
    const int ig = m0 + wr * 64 + i * 16 + kq * 4;
    #pragma unroll
    for (int j = 0; j < 4; ++j) {
      const int jg = n0 + wc * 64 + j * 16 + ln;
      f32x4 a = acc[i][j];
      if (MODE == M_QKV) {
        float bias = P.qkvb[jg];
        if (jg < 512) {
          bf16* d = P.qT + ((size_t)lb * NT + ig) * NC + jg;
          #pragma unroll
          for (int r = 0; r < 4; ++r) d[(size_t)r * NC] = __float2bfloat16(a[r] + bias);
        } else if (jg < 1024) {
          bf16* d = P.kfT + ((size_t)lb * NL + 256 + ig) * NC + (jg - 512);
          #pragma unroll
          for (int r = 0; r < 4; ++r) d[(size_t)r * NC] = __float2bfloat16(a[r] + bias);
        } else {
          u16x4 pk;
          #pragma unroll
          for (int r = 0; r < 4; ++r) pk[r] = f2bf_bits(a[r] + bias);
          *(u16x4*)(P.vf + ((size_t)lb * NC + (jg - 1024)) * NL + 256 + ig) = pk;
        }
      } else if (MODE == M_EKV) {
        float bias = P.ekvb[jg];
        if (jg < 512) {
          bf16* d = P.kfT + ((size_t)lb * NL + ig) * NC + jg;
          #pragma unroll
          for (int r = 0; r < 4; ++r) d[(size_t)r * NC] = __float2bfloat16(a[r] + bias);
        } else {
          u16x4 pk;
          #pragma unroll
          for (int r = 0; r < 4; ++r) pk[r] = f2bf_bits(a[r] + bias);
          *(u16x4*)(P.vf + ((size_t)lb * NC + (jg - 512)) * NL + ig) = pk;
        }
      } else if (MODE == M_LOG) {
        bf16* d = P.pr + ((size_t)lb * NT + ig) * NL + jg;
        #pragma unroll
        for (int r = 0; r < 4; ++r) d[(size_t)r * NL] = __float2bfloat16(a[r] * SCALE2);
      } else if (MODE == M_PV) {
        bf16* d = P.aT + ((size_t)lb * NT + ig) * NC + jg;
        #pragma unroll
        for (int r = 0; r < 4; ++r) d[(size_t)r * NC] = __float2bfloat16(a[r]);
      } else {  // M_PROJ: out[b][c][t] = 2*morph - x - (hout + bias)
        float bias = P.projb[jg];
        const size_t idx = ((size_t)gb * NC + jg) * NT + ig;
        float4 mo = *(const float4*)&P.morph[idx];
        float4 xx = *(const float4*)&P.x[idx];
        f32x4 o;
        o[0] = 2.0f * mo.x - xx.x - (a[0] + bias);
        o[1] = 2.0f * mo.y - xx.y - (a[1] + bias);
        o[2] = 2.0f * mo.z - xx.z - (a[2] + bias);
        o[3] = 2.0f * mo.w - xx.w - (a[3] + bias);
        *(f32x4*)&P.out[idx] = o;
      }
    }
  }
}

// ---------------- Row softmax over L=512 on bf16, one wave per row ---------
__global__ __launch_bounds__(256) void softmax_k(bf16* __restrict__ pr) {
  const size_t row = (size_t)blockIdx.x * 4 + (threadIdx.x >> 6);
  const int lane = threadIdx.x & 63;
  bf16* p = pr + row * NL + lane * 8;     // 8 contiguous bf16 per lane
  float v[8];
  float m = -1e30f;
  #pragma unroll
  for (int i = 0; i < 8; ++i) {
    v[i] = __bfloat162float(p[i]);
    m = fmaxf(m, v[i]);
  }
  #pragma unroll
  for (int off = 32; off; off >>= 1) m = fmaxf(m, __shfl_xor(m, off));
  float s = 0.f;
  #pragma unroll
  for (int i = 0; i < 8; ++i) { v[i] = __expf(v[i] - m); s += v[i]; }
  #pragma unroll
  for (int off = 32; off; off >>= 1) s += __shfl_xor(s, off);
  const float inv = 1.0f / s;
  #pragma unroll
  for (int i = 0; i < 8; ++i) p[i] = __float2bfloat16(v[i] * inv);
}

extern "C" void kernel_launch(void* const* d_in, const int* in_sizes, int n_in,
                              void* d_out, int out_size, void* d_ws, size_t ws_size,
                              hipStream_t stream) {
  const float* x     = (const float*)d_in[0];
  const float* morph = (const float*)d_in[1];
  const float* gnw   = (const float*)d_in[2];
  const float* gnb   = (const float*)d_in[3];
  const float* qkvw  = (const float*)d_in[4];
  const float* qkvb  = (const float*)d_in[5];
  const float* ekvw  = (const float*)d_in[6];
  const float* ekvb  = (const float*)d_in[7];
  const float* projw = (const float*)d_in[8];
  const float* projb = (const float*)d_in[9];

  // Workspace layout: bf16 weights (3 MB) + stats (32 KB) + per-batch bufs.
  bf16* wq = (bf16*)d_ws;            // 1536*512 = 786432
  bf16* we = wq + 786432;            // 1024*512 = 524288
  bf16* wp = we + 524288;            //  512*512 = 262144
  float* stats = (float*)(wp + 262144);  // 128*32*2 = 8192 floats
  bf16* pb = (bf16*)(stats + 8192);

  // Per-batch bf16 elems: hT 131072, mT 131072, qT 131072, kfT 262144,
  // vf 262144, pr 131072, aT 131072 -> 1,179,648 (2.36 MB).
  const size_t per_b = 1179648;
  const size_t fixed = (size_t)(786432 + 524288 + 262144) * 2 + 8192 * 4;
  int nbc = NB;
  while (nbc > 1 && fixed + (size_t)nbc * per_b * 2 > ws_size) nbc >>= 1;

  Params P;
  P.x = x; P.morph = morph; P.qkvb = qkvb; P.ekvb = ekvb; P.projb = projb;
  P.wq = wq; P.we = we; P.wp = wp;
  P.hT  = pb;                         pb += (size_t)nbc * 131072;
  P.mT  = pb;                         pb += (size_t)nbc * 131072;
  P.qT  = pb;                         pb += (size_t)nbc * 131072;
  P.kfT = pb;                         pb += (size_t)nbc * 262144;
  P.vf  = pb;                         pb += (size_t)nbc * 262144;
  P.pr  = pb;                         pb += (size_t)nbc * 131072;
  P.aT  = pb;
  P.out = (float*)d_out;

  gn_stats_k<<<dim3(NB * NG), dim3(256), 0, stream>>>(x, stats);
  cvt_k<<<dim3(3072), dim3(256), 0, stream>>>(qkvw, wq, 786432);
  cvt_k<<<dim3(2048), dim3(256), 0, stream>>>(ekvw, we, 524288);
  cvt_k<<<dim3(1024), dim3(256), 0, stream>>>(projw, wp, 262144);

  for (int b0 = 0; b0 < NB; b0 += nbc) {
    P.b0 = b0;
    transpose_k<1><<<dim3(8, 16, nbc), dim3(256), 0, stream>>>(x, P.hT, stats, gnw, gnb, b0);
    transpose_k<0><<<dim3(8, 16, nbc), dim3(256), 0, stream>>>(morph, P.mT, stats, gnw, gnb, b0);
    gemm_k<M_QKV> <<<dim3(12, 2, nbc), dim3(256), 0, stream>>>(P);
    gemm_k<M_EKV> <<<dim3(8, 2, nbc),  dim3(256), 0, stream>>>(P);
    gemm_k<M_LOG> <<<dim3(4, 2, nbc),  dim3(256), 0, stream>>>(P);
    softmax_k     <<<dim3(nbc * 64),   dim3(256), 0, stream>>>(P.pr);
    gemm_k<M_PV>  <<<dim3(4, 2, nbc),  dim3(256), 0, stream>>>(P);
    gemm_k<M_PROJ><<<dim3(4, 2, nbc),  dim3(256), 0, stream>>>(P);
  }
}

// Round 4
// 583.699 us; speedup vs baseline: 6.1097x; 1.0341x over previous
//
#include <hip/hip_runtime.h>
#include <hip/hip_bf16.h>
#include <math.h>

#define NB 128
#define NC 512
#define NT 256
#define NL 512
#define NG 32
#define SCALE2 0.04419417382415922f  // 1/sqrt(512)

typedef __attribute__((ext_vector_type(8))) short bf16x8;   // 8 bf16 = 4 VGPRs
typedef __attribute__((ext_vector_type(4))) float f32x4;
typedef __attribute__((ext_vector_type(4))) unsigned short u16x4;
typedef __hip_bfloat16 bf16;

struct Params {
  const float *x, *morph, *qkvb, *ekvb, *projb;
  const bf16 *wq, *we, *wp;
  bf16 *hT, *mT, *qT, *kfT, *vf, *pr, *aT;
  float *out;
  int b0;
};

enum { M_QKV = 0, M_EKV = 1, M_LOG = 2, M_PV = 3, M_PROJ = 4 };

__device__ inline unsigned short f2bf_bits(float f) {
  bf16 h = __float2bfloat16(f);
  return *reinterpret_cast<unsigned short*>(&h);
}

// Async global->LDS, 16 B per lane. LDS dest must be WAVE-UNIFORM base;
// lane l's data lands at lds + l*16 (m104/m108 semantics).
__device__ inline void gld16(const void* g, void* lds) {
  __builtin_amdgcn_global_load_lds(
      (const __attribute__((address_space(1))) unsigned int*)g,
      (__attribute__((address_space(3))) unsigned int*)lds, 16, 0, 0);
}

// ---------------- GroupNorm statistics over all 128 batches ----------------
__global__ __launch_bounds__(256) void gn_stats_k(const float* __restrict__ x,
                                                  float* __restrict__ stats) {
  const int bg = blockIdx.x;               // b*32 + g ; group = 4096 contiguous
  const float* p = x + (size_t)bg * 4096;
  float s = 0.f, s2 = 0.f;
  for (int i = threadIdx.x; i < 4096; i += 256) {
    float v = p[i];
    s += v; s2 += v * v;
  }
  for (int off = 32; off; off >>= 1) {
    s  += __shfl_down(s, off);
    s2 += __shfl_down(s2, off);
  }
  __shared__ float red[8];
  const int wave = threadIdx.x >> 6, lane = threadIdx.x & 63;
  if (lane == 0) { red[wave * 2] = s; red[wave * 2 + 1] = s2; }
  __syncthreads();
  if (threadIdx.x == 0) {
    float S = 0.f, S2 = 0.f;
    for (int w = 0; w < 4; ++w) { S += red[w * 2]; S2 += red[w * 2 + 1]; }
    float mu = S * (1.0f / 4096.0f);
    float var = S2 * (1.0f / 4096.0f) - mu * mu;
    stats[bg * 2]     = mu;
    stats[bg * 2 + 1] = rsqrtf(var + 1e-5f);
  }
}

// ---------------- fp32 -> bf16 weight conversion ----------------
__global__ __launch_bounds__(256) void cvt_k(const float* __restrict__ s,
                                             bf16* __restrict__ d, int n) {
  int i = blockIdx.x * 256 + threadIdx.x;
  if (i < n) d[i] = __float2bfloat16(s[i]);
}

// ------- merged [C][T] fp32 -> [T][C] bf16 transpose (x: groupnorm) --------
__global__ __launch_bounds__(256) void transpose2_k(const float* __restrict__ x,
                                                    const float* __restrict__ morph,
                                                    bf16* __restrict__ hT,
                                                    bf16* __restrict__ mT,
                                                    const float* __restrict__ stats,
                                                    const float* __restrict__ gnw,
                                                    const float* __restrict__ gnb,
                                                    int b0, int nbc) {
  __shared__ float sm[32][33];
  const int z = blockIdx.z;
  const int norm = (z < nbc) ? 1 : 0;
  const int lb = norm ? z : z - nbc;
  const int gb = b0 + lb;
  const float* src = norm ? x : morph;
  bf16* dst = norm ? hT : mT;
  const int c0 = blockIdx.y * 32, t0 = blockIdx.x * 32;
  const int tx = threadIdx.x & 31, ty = threadIdx.x >> 5;  // ty in [0,8)
  const float* s = src + ((size_t)gb * NC + c0) * NT + t0;
  #pragma unroll
  for (int j = 0; j < 4; ++j) {
    int c = ty + j * 8;
    float v = s[c * NT + tx];
    if (norm) {
      int cg = c0 + c;
      float mu = stats[(gb * NG + (cg >> 4)) * 2];
      float rs = stats[(gb * NG + (cg >> 4)) * 2 + 1];
      v = (v - mu) * rs * gnw[cg] + gnb[cg];
    }
    sm[c][tx] = v;
  }
  __syncthreads();
  bf16* d = dst + ((size_t)lb * NT + t0) * NC + c0;
  #pragma unroll
  for (int j = 0; j < 4; ++j)
    d[(size_t)(ty + j * 8) * NC + tx] = __float2bfloat16(sm[tx][ty + j * 8]);
}

// ---------------- Uniform MFMA GEMM: C[i][j] = sum_k A[i][k] * B[j][k] ------
// A: [M][512] bf16 row-major, B: [N][512] bf16 row-major, K = 512 always.
// Block: 256 thr (4 waves), tile 128x128, BK=32, global_load_lds staging into
// UNPADDED LDS (contiguous lane order required), 4x4 MFMA 16x16x32 per wave.
template <int MODE>
__global__ __launch_bounds__(256) void gemm_k(Params P) {
  __shared__ unsigned short As[128][32];   // 8 KB, unpadded (gld16 layout)
  __shared__ unsigned short Bs[128][32];
  const int lb = blockIdx.z, gb = P.b0 + lb;
  const int m0 = blockIdx.y * 128;
  const int n0 = blockIdx.x * 128;
  const int tid = threadIdx.x;
  const int lane = tid & 63, w = tid >> 6;
  const int wr = w >> 1, wc = w & 1;
  const int ln = lane & 15, kq = lane >> 4;

  const bf16 *Ab, *Bb;
  if (MODE == M_QKV)      { Ab = P.hT + (size_t)lb * NT * NC; Bb = P.wq; }
  else if (MODE == M_EKV) { Ab = P.mT + (size_t)lb * NT * NC; Bb = P.we; }
  else if (MODE == M_LOG) { Ab = P.qT + (size_t)lb * NT * NC; Bb = P.kfT + (size_t)lb * NL * NC; }
  else if (MODE == M_PV)  { Ab = P.pr + (size_t)lb * NT * NL; Bb = P.vf + (size_t)lb * NC * NL; }
  else                    { Ab = P.aT + (size_t)lb * NT * NC; Bb = P.wp; }

  const char* Abase = (const char*)(Ab + (size_t)m0 * 512);  // row stride 1024 B
  const char* Bbase = (const char*)(Bb + (size_t)n0 * 512);

  // Staging geometry: tile = 8 KB = 512 x 16B chunks; wave w covers chunks
  // [w*128, w*128+128) in two calls of 64. chunk c -> row c>>2, quarter c&3.
  const int r_lo = w * 32 + (lane >> 2);   // h=0 row
  const int cid16 = (lane & 3) * 16;       // byte offset within row

  f32x4 acc[4][4] = {};

  for (int k0 = 0; k0 < 512; k0 += 32) {
    const size_t kb = (size_t)k0 * 2 + cid16;
    #pragma unroll
    for (int h = 0; h < 2; ++h) {
      const int rw = r_lo + h * 16;
      gld16(Abase + (size_t)rw * 1024 + kb, (char*)As + w * 2048 + h * 1024);
      gld16(Bbase + (size_t)rw * 1024 + kb, (char*)Bs + w * 2048 + h * 1024);
    }
    __syncthreads();
    bf16x8 af[4], bfr[4];
    #pragma unroll
    for (int i = 0; i < 4; ++i)
      af[i] = *(const bf16x8*)&As[wr * 64 + i * 16 + ln][kq * 8];
    #pragma unroll
    for (int j = 0; j < 4; ++j)
      bfr[j] = *(const bf16x8*)&Bs[wc * 64 + j * 16 + ln][kq * 8];
    #pragma unroll
    for (int i = 0; i < 4; ++i)
      #pragma unroll
      for (int j = 0; j < 4; ++j)
        acc[i][j] = __builtin_amdgcn_mfma_f32_16x16x32_bf16(af[i], bfr[j], acc[i][j], 0, 0, 0);
    __syncthreads();
  }

  // Epilogue. D layout: col = lane&15 (j dim), row = (lane>>4)*4 + reg (i dim).
  #pragma unroll
  for (int i = 0; i < 4; ++i) {
    const int ig = m0 + wr * 64 + i * 16 + kq * 4;
    #pragma unroll
    for (int j = 0; j < 4; ++j) {
      const int jg = n0 + wc * 64 + j * 16 + ln;
      f32x4 a = acc[i][j];
      if (MODE == M_QKV) {
        float bias = P.qkvb[jg];
        if (jg < 512) {
          bf16* d = P.qT + ((size_t)lb * NT + ig) * NC + jg;
          #pragma unroll
          for (int r = 0; r < 4; ++r) d[(size_t)r * NC] = __float2bfloat16(a[r] + bias);
        } else if (jg < 1024) {
          bf16* d = P.kfT + ((size_t)lb * NL + 256 + ig) * NC + (jg - 512);
          #pragma unroll
          for (int r = 0; r < 4; ++r) d[(size_t)r * NC] = __float2bfloat16(a[r] + bias);
        } else {
          u16x4 pk;
          #pragma unroll
          for (int r = 0; r < 4; ++r) pk[r] = f2bf_bits(a[r] + bias);
          *(u16x4*)(P.vf + ((size_t)lb * NC + (jg - 1024)) * NL + 256 + ig) = pk;
        }
      } else if (MODE == M_EKV) {
        float bias = P.ekvb[jg];
        if (jg < 512) {
          bf16* d = P.kfT + ((size_t)lb * NL + ig) * NC + jg;
          #pragma unroll
          for (int r = 0; r < 4; ++r) d[(size_t)r * NC] = __float2bfloat16(a[r] + bias);
        } else {
          u16x4 pk;
          #pragma unroll
          for (int r = 0; r < 4; ++r) pk[r] = f2bf_bits(a[r] + bias);
          *(u16x4*)(P.vf + ((size_t)lb * NC + (jg - 512)) * NL + ig) = pk;
        }
      } else if (MODE == M_LOG) {
        bf16* d = P.pr + ((size_t)lb * NT + ig) * NL + jg;
        #pragma unroll
        for (int r = 0; r < 4; ++r) d[(size_t)r * NL] = __float2bfloat16(a[r] * SCALE2);
      } else if (MODE == M_PV) {
        bf16* d = P.aT + ((size_t)lb * NT + ig) * NC + jg;
        #pragma unroll
        for (int r = 0; r < 4; ++r) d[(size_t)r * NC] = __float2bfloat16(a[r]);
      } else {  // M_PROJ: out[b][c][t] = 2*morph - x - (hout + bias)
        float bias = P.projb[jg];
        const size_t idx = ((size_t)gb * NC + jg) * NT + ig;
        float4 mo = *(const float4*)&P.morph[idx];
        float4 xx = *(const float4*)&P.x[idx];
        f32x4 o;
        o[0] = 2.0f * mo.x - xx.x - (a[0] + bias);
        o[1] = 2.0f * mo.y - xx.y - (a[1] + bias);
        o[2] = 2.0f * mo.z - xx.z - (a[2] + bias);
        o[3] = 2.0f * mo.w - xx.w - (a[3] + bias);
        *(f32x4*)&P.out[idx] = o;
      }
    }
  }
}

// ---------------- Row softmax over L=512 on bf16, one wave per row ---------
__global__ __launch_bounds__(256) void softmax_k(bf16* __restrict__ pr) {
  const size_t row = (size_t)blockIdx.x * 4 + (threadIdx.x >> 6);
  const int lane = threadIdx.x & 63;
  bf16* p = pr + row * NL + lane * 8;     // 8 contiguous bf16 per lane
  float v[8];
  float m = -1e30f;
  #pragma unroll
  for (int i = 0; i < 8; ++i) {
    v[i] = __bfloat162float(p[i]);
    m = fmaxf(m, v[i]);
  }
  #pragma unroll
  for (int off = 32; off; off >>= 1) m = fmaxf(m, __shfl_xor(m, off));
  float s = 0.f;
  #pragma unroll
  for (int i = 0; i < 8; ++i) { v[i] = __expf(v[i] - m); s += v[i]; }
  #pragma unroll
  for (int off = 32; off; off >>= 1) s += __shfl_xor(s, off);
  const float inv = 1.0f / s;
  #pragma unroll
  for (int i = 0; i < 8; ++i) p[i] = __float2bfloat16(v[i] * inv);
}

extern "C" void kernel_launch(void* const* d_in, const int* in_sizes, int n_in,
                              void* d_out, int out_size, void* d_ws, size_t ws_size,
                              hipStream_t stream) {
  const float* x     = (const float*)d_in[0];
  const float* morph = (const float*)d_in[1];
  const float* gnw   = (const float*)d_in[2];
  const float* gnb   = (const float*)d_in[3];
  const float* qkvw  = (const float*)d_in[4];
  const float* qkvb  = (const float*)d_in[5];
  const float* ekvw  = (const float*)d_in[6];
  const float* ekvb  = (const float*)d_in[7];
  const float* projw = (const float*)d_in[8];
  const float* projb = (const float*)d_in[9];

  // Workspace: bf16 weights (3 MB) + stats (32 KB) + per-batch bufs.
  bf16* wq = (bf16*)d_ws;                // 1536*512 = 786432
  bf16* we = wq + 786432;                // 1024*512 = 524288
  bf16* wp = we + 524288;                //  512*512 = 262144
  float* stats = (float*)(wp + 262144);  // 8192 floats
  bf16* pb = (bf16*)(stats + 8192);

  // Per-batch bf16 elems (with aliasing aT==hT, pr==mT):
  // hT 131072, mT 131072, qT 131072, kfT 262144, vf 262144 = 917504 (1.75 MB)
  const size_t per_b = 917504;
  const size_t fixed = (size_t)(786432 + 524288 + 262144) * 2 + 8192 * 4;
  int nbc = NB;
  while (nbc > 1 && fixed + (size_t)nbc * per_b * 2 > ws_size) nbc >>= 1;

  Params P;
  P.x = x; P.morph = morph; P.qkvb = qkvb; P.ekvb = ekvb; P.projb = projb;
  P.wq = wq; P.we = we; P.wp = wp;
  P.hT  = pb;                         pb += (size_t)nbc * 131072;
  P.mT  = pb;                         pb += (size_t)nbc * 131072;
  P.qT  = pb;                         pb += (size_t)nbc * 131072;
  P.kfT = pb;                         pb += (size_t)nbc * 262144;
  P.vf  = pb;
  // Aliases (lifetimes disjoint within a chunk's kernel sequence):
  P.pr  = P.mT;   // mT dead after EKV; LOG writes pr, softmax/PV read it
  P.aT  = P.hT;   // hT dead after QKV; PV writes aT, PROJ reads it
  P.out = (float*)d_out;

  gn_stats_k<<<dim3(NB * NG), dim3(256), 0, stream>>>(x, stats);
  cvt_k<<<dim3(3072), dim3(256), 0, stream>>>(qkvw, wq, 786432);
  cvt_k<<<dim3(2048), dim3(256), 0, stream>>>(ekvw, we, 524288);
  cvt_k<<<dim3(1024), dim3(256), 0, stream>>>(projw, wp, 262144);

  for (int b0 = 0; b0 < NB; b0 += nbc) {
    P.b0 = b0;
    transpose2_k<<<dim3(8, 16, 2 * nbc), dim3(256), 0, stream>>>(
        x, morph, P.hT, P.mT, stats, gnw, gnb, b0, nbc);
    gemm_k<M_QKV> <<<dim3(12, 2, nbc), dim3(256), 0, stream>>>(P);
    gemm_k<M_EKV> <<<dim3(8, 2, nbc),  dim3(256), 0, stream>>>(P);
    gemm_k<M_LOG> <<<dim3(4, 2, nbc),  dim3(256), 0, stream>>>(P);
    softmax_k     <<<dim3(nbc * 64),   dim3(256), 0, stream>>>(P.pr);
    gemm_k<M_PV>  <<<dim3(4, 2, nbc),  dim3(256), 0, stream>>>(P);
    gemm_k<M_PROJ><<<dim3(4, 2, nbc),  dim3(256), 0, stream>>>(P);
  }
}

// Round 5
// 538.318 us; speedup vs baseline: 6.6248x; 1.0843x over previous
//
#include <hip/hip_runtime.h>
#include <hip/hip_bf16.h>
#include <math.h>

#define NB 128
#define NC 512
#define NT 256
#define NL 512
#define NG 32
#define SCALE2 0.04419417382415922f  // 1/sqrt(512)

typedef __attribute__((ext_vector_type(8))) short bf16x8;
typedef __attribute__((ext_vector_type(4))) float f32x4;
typedef __attribute__((ext_vector_type(4))) unsigned short u16x4;
typedef __attribute__((ext_vector_type(8))) unsigned short u16x8;
typedef __hip_bfloat16 bf16;

struct Params {
  const float *x, *morph, *qkvb, *ekvb, *projb;
  const bf16 *wq, *we, *wp;
  bf16 *hT, *mT, *qT, *kfT, *vf;
  float *out;
  int b0;
};

enum { M_QKV = 0, M_EKV = 1 };

__device__ inline unsigned short f2bf_bits(float f) {
  bf16 h = __float2bfloat16(f);
  return *reinterpret_cast<unsigned short*>(&h);
}

// Async global->LDS, 16 B per lane; LDS dest wave-uniform, lane l -> lds+l*16.
__device__ inline void gld16(const void* g, void* lds) {
  __builtin_amdgcn_global_load_lds(
      (const __attribute__((address_space(1))) unsigned int*)g,
      (__attribute__((address_space(3))) unsigned int*)lds, 16, 0, 0);
}

// ---------------- GroupNorm statistics (float4 loads) ----------------
__global__ __launch_bounds__(256) void gn_stats_k(const float* __restrict__ x,
                                                  float* __restrict__ stats) {
  const int bg = blockIdx.x;                    // b*32+g; group = 4096 contiguous
  const float4* p4 = (const float4*)(x + (size_t)bg * 4096);
  float s = 0.f, s2 = 0.f;
  #pragma unroll
  for (int i = 0; i < 4; ++i) {
    float4 v = p4[threadIdx.x + i * 256];
    s  += v.x + v.y + v.z + v.w;
    s2 += v.x * v.x + v.y * v.y + v.z * v.z + v.w * v.w;
  }
  #pragma unroll
  for (int off = 32; off; off >>= 1) {
    s  += __shfl_down(s, off);
    s2 += __shfl_down(s2, off);
  }
  __shared__ float red[8];
  const int wave = threadIdx.x >> 6, lane = threadIdx.x & 63;
  if (lane == 0) { red[wave * 2] = s; red[wave * 2 + 1] = s2; }
  __syncthreads();
  if (threadIdx.x == 0) {
    float S = 0.f, S2 = 0.f;
    for (int w = 0; w < 4; ++w) { S += red[w * 2]; S2 += red[w * 2 + 1]; }
    float mu = S * (1.0f / 4096.0f);
    float var = S2 * (1.0f / 4096.0f) - mu * mu;
    stats[bg * 2]     = mu;
    stats[bg * 2 + 1] = rsqrtf(var + 1e-5f);
  }
}

// ---------------- fp32 -> bf16 weight conversion ----------------
__global__ __launch_bounds__(256) void cvt_k(const float* __restrict__ s,
                                             bf16* __restrict__ d, int n) {
  int i = blockIdx.x * 256 + threadIdx.x;
  if (i < n) d[i] = __float2bfloat16(s[i]);
}

// -------- merged [C][T] fp32 -> [T][C] bf16 transpose, 64x64 tiles ---------
// z < nbc: x with groupnorm -> hT ; z >= nbc: morph -> mT.
__global__ __launch_bounds__(256) void transpose2_k(const float* __restrict__ x,
                                                    const float* __restrict__ morph,
                                                    bf16* __restrict__ hT,
                                                    bf16* __restrict__ mT,
                                                    const float* __restrict__ stats,
                                                    const float* __restrict__ gnw,
                                                    const float* __restrict__ gnb,
                                                    int b0, int nbc) {
  __shared__ float sm[64][65];
  const int z = blockIdx.z;
  const int norm = (z < nbc) ? 1 : 0;
  const int lb = norm ? z : z - nbc;
  const int gb = b0 + lb;
  const float* src = norm ? x : morph;
  bf16* dst = norm ? hT : mT;
  const int t0 = blockIdx.x * 64, c0 = blockIdx.y * 64;
  const int tx = threadIdx.x & 15, ty = threadIdx.x >> 4;  // tx: t-quad, ty: 16 c
  #pragma unroll
  for (int ci = 0; ci < 4; ++ci) {
    const int c = ty + ci * 16;
    const int cg = c0 + c;
    float4 v = *(const float4*)&src[((size_t)gb * NC + cg) * NT + t0 + tx * 4];
    if (norm) {
      float mu = stats[(gb * NG + (cg >> 4)) * 2];
      float rs = stats[(gb * NG + (cg >> 4)) * 2 + 1];
      float wv = gnw[cg], bv = gnb[cg];
      v.x = (v.x - mu) * rs * wv + bv;
      v.y = (v.y - mu) * rs * wv + bv;
      v.z = (v.z - mu) * rs * wv + bv;
      v.w = (v.w - mu) * rs * wv + bv;
    }
    sm[c][tx * 4 + 0] = v.x; sm[c][tx * 4 + 1] = v.y;
    sm[c][tx * 4 + 2] = v.z; sm[c][tx * 4 + 3] = v.w;
  }
  __syncthreads();
  const int t = threadIdx.x >> 2, cq = threadIdx.x & 3;   // 16 contiguous c/thread
  u16x8 pk0, pk1;
  #pragma unroll
  for (int k = 0; k < 8; ++k) pk0[k] = f2bf_bits(sm[cq * 16 + k][t]);
  #pragma unroll
  for (int k = 0; k < 8; ++k) pk1[k] = f2bf_bits(sm[cq * 16 + 8 + k][t]);
  bf16* d = dst + ((size_t)lb * NT + t0 + t) * NC + c0 + cq * 16;
  *(u16x8*)d = pk0;
  *(u16x8*)(d + 8) = pk1;
}

// ------- MFMA GEMM (QKV / EKV): C[i][j] = sum_k A[i][k] * B[j][k] ----------
// Grid: (nbc, M/128, N/128) — batch in x for XCD L2 locality.
template <int MODE>
__global__ __launch_bounds__(256) void gemm_k(Params P) {
  __shared__ unsigned short As[128][32];
  __shared__ unsigned short Bs[128][32];
  const int lb = blockIdx.x;
  const int m0 = blockIdx.y * 128;
  const int n0 = blockIdx.z * 128;
  const int tid = threadIdx.x;
  const int lane = tid & 63, w = tid >> 6;
  const int wr = w >> 1, wc = w & 1;
  const int ln = lane & 15, kq = lane >> 4;

  const bf16 *Ab, *Bb;
  if (MODE == M_QKV) { Ab = P.hT + (size_t)lb * NT * NC; Bb = P.wq; }
  else               { Ab = P.mT + (size_t)lb * NT * NC; Bb = P.we; }

  const char* Abase = (const char*)(Ab + (size_t)m0 * 512);
  const char* Bbase = (const char*)(Bb + (size_t)n0 * 512);

  const int r_lo = w * 32 + (lane >> 2);
  const int cid16 = (lane & 3) * 16;

  f32x4 acc[4][4] = {};

  for (int k0 = 0; k0 < 512; k0 += 32) {
    const size_t kb = (size_t)k0 * 2 + cid16;
    #pragma unroll
    for (int h = 0; h < 2; ++h) {
      const int rw = r_lo + h * 16;
      gld16(Abase + (size_t)rw * 1024 + kb, (char*)As + w * 2048 + h * 1024);
      gld16(Bbase + (size_t)rw * 1024 + kb, (char*)Bs + w * 2048 + h * 1024);
    }
    __syncthreads();
    bf16x8 af[4], bfr[4];
    #pragma unroll
    for (int i = 0; i < 4; ++i)
      af[i] = *(const bf16x8*)&As[wr * 64 + i * 16 + ln][kq * 8];
    #pragma unroll
    for (int j = 0; j < 4; ++j)
      bfr[j] = *(const bf16x8*)&Bs[wc * 64 + j * 16 + ln][kq * 8];
    #pragma unroll
    for (int i = 0; i < 4; ++i)
      #pragma unroll
      for (int j = 0; j < 4; ++j)
        acc[i][j] = __builtin_amdgcn_mfma_f32_16x16x32_bf16(af[i], bfr[j], acc[i][j], 0, 0, 0);
    __syncthreads();
  }

  #pragma unroll
  for (int i = 0; i < 4; ++i) {
    const int ig = m0 + wr * 64 + i * 16 + kq * 4;
    #pragma unroll
    for (int j = 0; j < 4; ++j) {
      const int jg = n0 + wc * 64 + j * 16 + ln;
      f32x4 a = acc[i][j];
      if (MODE == M_QKV) {
        float bias = P.qkvb[jg];
        if (jg < 512) {
          bf16* d = P.qT + ((size_t)lb * NT + ig) * NC + jg;
          #pragma unroll
          for (int r = 0; r < 4; ++r) d[(size_t)r * NC] = __float2bfloat16(a[r] + bias);
        } else if (jg < 1024) {
          bf16* d = P.kfT + ((size_t)lb * NL + 256 + ig) * NC + (jg - 512);
          #pragma unroll
          for (int r = 0; r < 4; ++r) d[(size_t)r * NC] = __float2bfloat16(a[r] + bias);
        } else {
          u16x4 pk;
          #pragma unroll
          for (int r = 0; r < 4; ++r) pk[r] = f2bf_bits(a[r] + bias);
          *(u16x4*)(P.vf + ((size_t)lb * NC + (jg - 1024)) * NL + 256 + ig) = pk;
        }
      } else {  // M_EKV
        float bias = P.ekvb[jg];
        if (jg < 512) {
          bf16* d = P.kfT + ((size_t)lb * NL + ig) * NC + jg;
          #pragma unroll
          for (int r = 0; r < 4; ++r) d[(size_t)r * NC] = __float2bfloat16(a[r] + bias);
        } else {
          u16x4 pk;
          #pragma unroll
          for (int r = 0; r < 4; ++r) pk[r] = f2bf_bits(a[r] + bias);
          *(u16x4*)(P.vf + ((size_t)lb * NC + (jg - 512)) * NL + ig) = pk;
        }
      }
    }
  }
}

// ---------------- Fused attention: logits+softmax+PV+proj+residual ---------
// Grid (nbc, 8): block = (batch, 32-row Q-tile). 256 threads / 4 waves.
// Wave w owns column range [w*128, w*128+128) of every 512-wide stage.
__global__ __launch_bounds__(256) void attn_k(Params P) {
  __shared__ unsigned short Abuf[32][32];    // 2 KB   q-tile k-slice
  __shared__ unsigned short Bbuf[512][32];   // 32 KB  full-N B k-slice
  __shared__ unsigned short Pbuf[32][520];   // 33 KB  P / O roundtrip (pad 8)
  __shared__ float redm[4][32];
  __shared__ float reds[4][32];

  const int lb = blockIdx.x, gb = P.b0 + lb;
  const int t0 = blockIdx.y * 32;
  const int tid = threadIdx.x;
  const int lane = tid & 63, w = tid >> 6;
  const int ln = lane & 15, kq = lane >> 4;
  const int srow = lane >> 2;          // staging row within 16
  const int scol = (lane & 3) * 16;    // staging byte offset within 64B row

  const char* qg  = (const char*)(P.qT  + ((size_t)lb * NT + t0) * NC);
  const char* kg  = (const char*)(P.kfT + (size_t)lb * NL * NC);
  const char* vg  = (const char*)(P.vf  + (size_t)lb * NC * NL);
  const char* wpg = (const char*)P.wp;

  f32x4 sa[2][8] = {};
  bf16x8 af[2], bfr[8];

  // ---- Phase 1: S = q . kf^T ----
  for (int k0 = 0; k0 < 512; k0 += 32) {
    const size_t koff = (size_t)k0 * 2 + scol;
    if (w < 2)
      gld16(qg + (size_t)(w * 16 + srow) * 1024 + koff, (char*)Abuf + w * 1024);
    #pragma unroll
    for (int h = 0; h < 8; ++h)
      gld16(kg + (size_t)(w * 128 + h * 16 + srow) * 1024 + koff,
            (char*)Bbuf + w * 8192 + h * 1024);
    __syncthreads();
    af[0] = *(const bf16x8*)&Abuf[ln][kq * 8];
    af[1] = *(const bf16x8*)&Abuf[16 + ln][kq * 8];
    #pragma unroll
    for (int j = 0; j < 8; ++j)
      bfr[j] = *(const bf16x8*)&Bbuf[w * 128 + j * 16 + ln][kq * 8];
    #pragma unroll
    for (int i = 0; i < 2; ++i)
      #pragma unroll
      for (int j = 0; j < 8; ++j)
        sa[i][j] = __builtin_amdgcn_mfma_f32_16x16x32_bf16(af[i], bfr[j], sa[i][j], 0, 0, 0);
    __syncthreads();
  }

  // ---- softmax over L=512 (rows: i*16 + kq*4 + r) ----
  float mx[2][4], sum[2][4], inv[2][4];
  #pragma unroll
  for (int i = 0; i < 2; ++i)
    #pragma unroll
    for (int r = 0; r < 4; ++r) {
      float m = -1e30f;
      #pragma unroll
      for (int j = 0; j < 8; ++j) m = fmaxf(m, sa[i][j][r]);
      mx[i][r] = m;
    }
  #pragma unroll
  for (int off = 1; off < 16; off <<= 1)
    #pragma unroll
    for (int i = 0; i < 2; ++i)
      #pragma unroll
      for (int r = 0; r < 4; ++r) mx[i][r] = fmaxf(mx[i][r], __shfl_xor(mx[i][r], off));
  if (ln == 0)
    #pragma unroll
    for (int i = 0; i < 2; ++i)
      #pragma unroll
      for (int r = 0; r < 4; ++r) redm[w][i * 16 + kq * 4 + r] = mx[i][r];
  __syncthreads();
  #pragma unroll
  for (int i = 0; i < 2; ++i)
    #pragma unroll
    for (int r = 0; r < 4; ++r) {
      const int row = i * 16 + kq * 4 + r;
      mx[i][r] = fmaxf(fmaxf(redm[0][row], redm[1][row]),
                       fmaxf(redm[2][row], redm[3][row]));
      sum[i][r] = 0.f;
    }
  #pragma unroll
  for (int i = 0; i < 2; ++i)
    #pragma unroll
    for (int j = 0; j < 8; ++j)
      #pragma unroll
      for (int r = 0; r < 4; ++r) {
        float e = __expf(SCALE2 * (sa[i][j][r] - mx[i][r]));
        sa[i][j][r] = e;
        sum[i][r] += e;
      }
  #pragma unroll
  for (int off = 1; off < 16; off <<= 1)
    #pragma unroll
    for (int i = 0; i < 2; ++i)
      #pragma unroll
      for (int r = 0; r < 4; ++r) sum[i][r] += __shfl_xor(sum[i][r], off);
  if (ln == 0)
    #pragma unroll
    for (int i = 0; i < 2; ++i)
      #pragma unroll
      for (int r = 0; r < 4; ++r) reds[w][i * 16 + kq * 4 + r] = sum[i][r];
  __syncthreads();
  #pragma unroll
  for (int i = 0; i < 2; ++i)
    #pragma unroll
    for (int r = 0; r < 4; ++r) {
      const int row = i * 16 + kq * 4 + r;
      inv[i][r] = 1.0f / (reds[0][row] + reds[1][row] + reds[2][row] + reds[3][row]);
    }
  #pragma unroll
  for (int i = 0; i < 2; ++i)
    #pragma unroll
    for (int j = 0; j < 8; ++j)
      #pragma unroll
      for (int r = 0; r < 4; ++r)
        Pbuf[i * 16 + kq * 4 + r][w * 128 + j * 16 + ln] = f2bf_bits(sa[i][j][r] * inv[i][r]);
  __syncthreads();

  // ---- Phase 2: O = P . vf^T  (A-frags straight from Pbuf) ----
  f32x4 oa[2][8] = {};
  for (int k0 = 0; k0 < 512; k0 += 32) {
    const size_t koff = (size_t)k0 * 2 + scol;
    #pragma unroll
    for (int h = 0; h < 8; ++h)
      gld16(vg + (size_t)(w * 128 + h * 16 + srow) * 1024 + koff,
            (char*)Bbuf + w * 8192 + h * 1024);
    __syncthreads();
    af[0] = *(const bf16x8*)&Pbuf[ln][k0 + kq * 8];
    af[1] = *(const bf16x8*)&Pbuf[16 + ln][k0 + kq * 8];
    #pragma unroll
    for (int j = 0; j < 8; ++j)
      bfr[j] = *(const bf16x8*)&Bbuf[w * 128 + j * 16 + ln][kq * 8];
    #pragma unroll
    for (int i = 0; i < 2; ++i)
      #pragma unroll
      for (int j = 0; j < 8; ++j)
        oa[i][j] = __builtin_amdgcn_mfma_f32_16x16x32_bf16(af[i], bfr[j], oa[i][j], 0, 0, 0);
    __syncthreads();
  }

  // ---- O -> Pbuf (bf16) for phase 3 ----
  #pragma unroll
  for (int i = 0; i < 2; ++i)
    #pragma unroll
    for (int j = 0; j < 8; ++j)
      #pragma unroll
      for (int r = 0; r < 4; ++r)
        Pbuf[i * 16 + kq * 4 + r][w * 128 + j * 16 + ln] = f2bf_bits(oa[i][j][r]);
  __syncthreads();

  // ---- Phase 3: Z = O . wp^T ----
  f32x4 za[2][8] = {};
  for (int k0 = 0; k0 < 512; k0 += 32) {
    const size_t koff = (size_t)k0 * 2 + scol;
    #pragma unroll
    for (int h = 0; h < 8; ++h)
      gld16(wpg + (size_t)(w * 128 + h * 16 + srow) * 1024 + koff,
            (char*)Bbuf + w * 8192 + h * 1024);
    __syncthreads();
    af[0] = *(const bf16x8*)&Pbuf[ln][k0 + kq * 8];
    af[1] = *(const bf16x8*)&Pbuf[16 + ln][k0 + kq * 8];
    #pragma unroll
    for (int j = 0; j < 8; ++j)
      bfr[j] = *(const bf16x8*)&Bbuf[w * 128 + j * 16 + ln][kq * 8];
    #pragma unroll
    for (int i = 0; i < 2; ++i)
      #pragma unroll
      for (int j = 0; j < 8; ++j)
        za[i][j] = __builtin_amdgcn_mfma_f32_16x16x32_bf16(af[i], bfr[j], za[i][j], 0, 0, 0);
    __syncthreads();
  }

  // ---- epilogue: out[b][c][t] = 2*morph - x - (z + projb[c]) ----
  #pragma unroll
  for (int i = 0; i < 2; ++i) {
    const int trow = t0 + i * 16 + kq * 4;
    #pragma unroll
    for (int j = 0; j < 8; ++j) {
      const int c = w * 128 + j * 16 + ln;
      const float bias = P.projb[c];
      const size_t idx = ((size_t)gb * NC + c) * NT + trow;
      float4 mo = *(const float4*)&P.morph[idx];
      float4 xx = *(const float4*)&P.x[idx];
      f32x4 o;
      o[0] = 2.0f * mo.x - xx.x - (za[i][j][0] + bias);
      o[1] = 2.0f * mo.y - xx.y - (za[i][j][1] + bias);
      o[2] = 2.0f * mo.z - xx.z - (za[i][j][2] + bias);
      o[3] = 2.0f * mo.w - xx.w - (za[i][j][3] + bias);
      *(f32x4*)&P.out[idx] = o;
    }
  }
}

extern "C" void kernel_launch(void* const* d_in, const int* in_sizes, int n_in,
                              void* d_out, int out_size, void* d_ws, size_t ws_size,
                              hipStream_t stream) {
  const float* x     = (const float*)d_in[0];
  const float* morph = (const float*)d_in[1];
  const float* gnw   = (const float*)d_in[2];
  const float* gnb   = (const float*)d_in[3];
  const float* qkvw  = (const float*)d_in[4];
  const float* qkvb  = (const float*)d_in[5];
  const float* ekvw  = (const float*)d_in[6];
  const float* ekvb  = (const float*)d_in[7];
  const float* projw = (const float*)d_in[8];
  const float* projb = (const float*)d_in[9];

  bf16* wq = (bf16*)d_ws;                // 786432
  bf16* we = wq + 786432;                // 524288
  bf16* wp = we + 524288;                // 262144
  float* stats = (float*)(wp + 262144);  // 8192 floats
  bf16* pb = (bf16*)(stats + 8192);

  // Per-batch bf16: hT 131072 + mT 131072 + qT 131072 + kfT 262144 + vf 262144
  const size_t per_b = 917504;
  const size_t fixed = (size_t)(786432 + 524288 + 262144) * 2 + 8192 * 4;
  int nbc = NB;
  while (nbc > 1 && fixed + (size_t)nbc * per_b * 2 > ws_size) nbc >>= 1;

  Params P;
  P.x = x; P.morph = morph; P.qkvb = qkvb; P.ekvb = ekvb; P.projb = projb;
  P.wq = wq; P.we = we; P.wp = wp;
  P.hT  = pb;  pb += (size_t)nbc * 131072;
  P.mT  = pb;  pb += (size_t)nbc * 131072;
  P.qT  = pb;  pb += (size_t)nbc * 131072;
  P.kfT = pb;  pb += (size_t)nbc * 262144;
  P.vf  = pb;
  P.out = (float*)d_out;

  gn_stats_k<<<dim3(NB * NG), dim3(256), 0, stream>>>(x, stats);
  cvt_k<<<dim3(3072), dim3(256), 0, stream>>>(qkvw, wq, 786432);
  cvt_k<<<dim3(2048), dim3(256), 0, stream>>>(ekvw, we, 524288);
  cvt_k<<<dim3(1024), dim3(256), 0, stream>>>(projw, wp, 262144);

  for (int b0 = 0; b0 < NB; b0 += nbc) {
    P.b0 = b0;
    transpose2_k<<<dim3(4, 8, 2 * nbc), dim3(256), 0, stream>>>(
        x, morph, P.hT, P.mT, stats, gnw, gnb, b0, nbc);
    gemm_k<M_QKV><<<dim3(nbc, 2, 12), dim3(256), 0, stream>>>(P);
    gemm_k<M_EKV><<<dim3(nbc, 2, 8),  dim3(256), 0, stream>>>(P);
    attn_k       <<<dim3(nbc, 8),     dim3(256), 0, stream>>>(P);
  }
}